// Round 10
// baseline (266.729 us; speedup 1.0000x reference)
//
#include <hip/hip_runtime.h>

// Sigma-delta integrate-and-fire vs a float64 numpy reference.
// History: r3 serial f64 fold (1 wave/CU) absmax=0.0 @ 90.8us kernel.
// r6 two-pass G=16 absmax=0.0, k1+k2 ~75us (inferred; kernels dropped below
// the harness's 79us poison-fill dispatches in the top-5 window).
// r8: float4 attempt failed to COMPILE (__builtin_nontemporal_store rejects
// HIP_vector_type). r9 (this, resubmitted after GPU timeout): same design
// with clang ext_vector_type vectors, which the nontemporal builtins accept.
//
// Design: float4 along u (4 chains/thread, 16B loads/NT-stores) + G=64
// groups -> (B*U/4)*G = 262144 threads = 4096 waves = 16/CU, L=32 serial.
// Pass 1 (k1): thread (b,g,u4) folds rd_i = fl64((f64)relu(x_i)*0.001) over
//   its L-element group for 4 adjacent u, serial f64 order -> S[b][g][u].
// Pass 2 (k2): single-pass prefix fold of S (canonical order), boundary
//   values bit-exact vs neighbor threads' expressions, re-read x (L3-hot),
//   recompute in-group fold (bit-identical to k1), floor, NT-store
//   (f - fprev)*1000.
//
// Boundary exactness (group-count independent): fprev_g =
// floor(fl(fl(v0+P_{g-1})+S_{g-1})) is exactly thread g-1's last cum floor;
// base_g = fl(v0 + fl(P_{g-1}+S_{g-1})) = fl(v0+P_g) in the same fold order
// all threads use. Only deviation from the monolithic f64 fold: prefix
// regrouping ~1e-13 vs ~1e-8 min cum-to-integer distance -> no floor flips
// (absmax measured 0.0 twice). Spike formed in f64, one cast: exact.

typedef float  f32x4 __attribute__((ext_vector_type(4)));
typedef double f64x4 __attribute__((ext_vector_type(4)));

__global__ __launch_bounds__(256, 4)
void sdiaf_k1_sums_v4(const float* __restrict__ x,
                      double* __restrict__ S,
                      int T, int U, int G, int totalV /* = (B*U/4)*G */) {
#pragma clang fp contract(off)
    const int flat = blockIdx.x * blockDim.x + threadIdx.x;  // ((b*G)+g)*(U/4)+u4
    if (flat >= totalV) return;
    const int U4 = U >> 2;
    const int u4 = flat % U4;
    const int bg = flat / U4;
    const int g = bg % G;
    const int b = bg / G;
    const int L = T / G;

    const float* __restrict__ xp =
        x + ((size_t)b * T + (size_t)g * L) * (size_t)U + ((size_t)u4 << 2);

    double s0 = 0.0, s1 = 0.0, s2 = 0.0, s3 = 0.0;
#pragma unroll 4
    for (int i = 0; i < L; ++i) {
        const f32x4 v = __builtin_nontemporal_load(
            reinterpret_cast<const f32x4*>(&xp[(size_t)i * U]));
        s0 = s0 + (double)fmaxf(v.x, 0.0f) * 0.001;   // serial f64 fold/chain
        s1 = s1 + (double)fmaxf(v.y, 0.0f) * 0.001;
        s2 = s2 + (double)fmaxf(v.z, 0.0f) * 0.001;
        s3 = s3 + (double)fmaxf(v.w, 0.0f) * 0.001;
    }
    f64x4 sv; sv.x = s0; sv.y = s1; sv.z = s2; sv.w = s3;
    *reinterpret_cast<f64x4*>(
        S + (((size_t)b * G + g) * (size_t)U + ((size_t)u4 << 2))) = sv;
}

__global__ __launch_bounds__(256, 4)
void sdiaf_k2_emit_v4(const float* __restrict__ x,
                      const float* __restrict__ v0,
                      const double* __restrict__ S,
                      float* __restrict__ out,
                      int T, int U, int G, int totalV) {
#pragma clang fp contract(off)
    const int flat = blockIdx.x * blockDim.x + threadIdx.x;
    if (flat >= totalV) return;
    const int U4 = U >> 2;
    const int u4 = flat % U4;
    const int bg = flat / U4;
    const int g = bg % G;        // wave-uniform (U4 = 128 is a multiple of 64)
    const int b = bg / G;
    const int L = T / G;

    const f32x4 v0v = *reinterpret_cast<const f32x4*>(
        &v0[(size_t)b * U + ((size_t)u4 << 2)]);
    const double v0d0 = (double)v0v.x, v0d1 = (double)v0v.y,
                 v0d2 = (double)v0v.z, v0d3 = (double)v0v.w;

    const double* __restrict__ Sp =
        S + ((size_t)b * G) * (size_t)U + ((size_t)u4 << 2);

    double base0, base1, base2, base3, fp0, fp1, fp2, fp3;
    if (g == 0) {
        base0 = v0d0; base1 = v0d1; base2 = v0d2; base3 = v0d3;
        fp0 = floor(v0d0); fp1 = floor(v0d1); fp2 = floor(v0d2); fp3 = floor(v0d3);
    } else {
        double P0 = 0.0, P1 = 0.0, P2 = 0.0, P3 = 0.0;
        for (int j = 0; j < g - 1; ++j) {             // serial f64, uniform trips
            const f64x4 sv = *reinterpret_cast<const f64x4*>(&Sp[(size_t)j * U]);
            P0 = P0 + sv.x; P1 = P1 + sv.y; P2 = P2 + sv.z; P3 = P3 + sv.w;
        }
        const f64x4 sl = *reinterpret_cast<const f64x4*>(&Sp[(size_t)(g - 1) * U]);
        fp0 = floor((v0d0 + P0) + sl.x);  // == thread g-1's last floor, bit-exact
        fp1 = floor((v0d1 + P1) + sl.y);
        fp2 = floor((v0d2 + P2) + sl.z);
        fp3 = floor((v0d3 + P3) + sl.w);
        base0 = v0d0 + (P0 + sl.x);       // == fl(v0 + P_g), canonical order
        base1 = v0d1 + (P1 + sl.y);
        base2 = v0d2 + (P2 + sl.z);
        base3 = v0d3 + (P3 + sl.w);
    }

    const size_t off0 =
        ((size_t)b * T + (size_t)g * L) * (size_t)U + ((size_t)u4 << 2);
    const float* __restrict__ xp = x + off0;
    float* __restrict__ op = out + off0;

    double s0 = 0.0, s1 = 0.0, s2 = 0.0, s3 = 0.0;
#pragma unroll 4
    for (int i = 0; i < L; ++i) {
        const f32x4 v = __builtin_nontemporal_load(
            reinterpret_cast<const f32x4*>(&xp[(size_t)i * U]));
        f32x4 o;
        s0 = s0 + (double)fmaxf(v.x, 0.0f) * 0.001;   // bit-identical to k1
        { double f = floor(base0 + s0); o.x = (float)((f - fp0) * 1000.0); fp0 = f; }
        s1 = s1 + (double)fmaxf(v.y, 0.0f) * 0.001;
        { double f = floor(base1 + s1); o.y = (float)((f - fp1) * 1000.0); fp1 = f; }
        s2 = s2 + (double)fmaxf(v.z, 0.0f) * 0.001;
        { double f = floor(base2 + s2); o.z = (float)((f - fp2) * 1000.0); fp2 = f; }
        s3 = s3 + (double)fmaxf(v.w, 0.0f) * 0.001;
        { double f = floor(base3 + s3); o.w = (float)((f - fp3) * 1000.0); fp3 = f; }
        __builtin_nontemporal_store(o, reinterpret_cast<f32x4*>(&op[(size_t)i * U]));
    }
}

// Known-good round-3 fallback (serial per-(b,u) f64 fold).
__global__ __launch_bounds__(64, 1)
void sdiaf_serial_f64(const float* __restrict__ x,
                      const float* __restrict__ v0,
                      float* __restrict__ out,
                      int T, int U, int total) {
#pragma clang fp contract(off)
    const int idx = blockIdx.x * blockDim.x + threadIdx.x;
    if (idx >= total) return;
    const int b = idx / U;
    const int u = idx - b * U;
    const double v0d = (double)v0[idx];
    double fprev = floor(v0d);
    double s = 0.0;
    const size_t base = (size_t)b * (size_t)T * (size_t)U + (size_t)u;
    const float* xp = x + base;
    float* op = out + base;
#pragma unroll 8
    for (int t = 0; t < T; ++t) {
        double rd = (double)fmaxf(xp[(size_t)t * U], 0.0f) * 0.001;
        s = s + rd;
        double c = v0d + s;
        double f = floor(c);
        op[(size_t)t * U] = (float)((f - fprev) * 1000.0);
        fprev = f;
    }
}

extern "C" void kernel_launch(void* const* d_in, const int* in_sizes, int n_in,
                              void* d_out, int out_size, void* d_ws, size_t ws_size,
                              hipStream_t stream) {
    const float* x  = (const float*)d_in[0];
    const float* v0 = (const float*)d_in[1];
    float* out = (float*)d_out;

    const int U = 512;                    // fixed by the problem
    const int total = in_sizes[1];        // B*U = 16384
    const int T = in_sizes[0] / total;    // 2048

    // Largest G the workspace supports (S = total*G doubles).
    int G = 0;
    if ((U % 4) == 0) {
        if ((T % 64) == 0 && ws_size >= (size_t)total * 64 * sizeof(double))
            G = 64;                        // 8 MB ws, 4096 waves (16/CU)
        else if ((T % 32) == 0 && ws_size >= (size_t)total * 32 * sizeof(double))
            G = 32;
        else if ((T % 16) == 0 && ws_size >= (size_t)total * 16 * sizeof(double))
            G = 16;
    }

    if (G > 0) {
        double* S = (double*)d_ws;
        const int totalV = (total / 4) * G;          // 262144 for G=64
        const int block = 256;
        const int grid = (totalV + block - 1) / block;
        sdiaf_k1_sums_v4<<<grid, block, 0, stream>>>(x, S, T, U, G, totalV);
        sdiaf_k2_emit_v4<<<grid, block, 0, stream>>>(x, v0, S, out, T, U, G, totalV);
    } else {
        const int block = 64;
        const int grid = (total + block - 1) / block;
        sdiaf_serial_f64<<<grid, block, 0, stream>>>(x, v0, out, T, U, total);
    }
}